// Round 14
// baseline (211.854 us; speedup 1.0000x reference)
//
#include <hip/hip_runtime.h>
#include <hip/hip_bf16.h>
#include <stdint.h>

// Problem constants
#define B_    16
#define N_    256
#define HID_  512
#define H_    8
#define DK_   64
#define FEAT_ 8
#define MLPH_ 64
#define LAM_  0.1f
#define SCALE_ 0.125f   // DK^-0.5

typedef short bf16x8 __attribute__((ext_vector_type(8)));
typedef float f32x4  __attribute__((ext_vector_type(4)));

union U8 { uint4 u; bf16x8 h; ushort s[8]; };

__device__ __forceinline__ uint16_t f32_to_bf16(float x) {
    uint32_t u = __float_as_uint(x);
    u += 0x7fffu + ((u >> 16) & 1u);      // RNE (no NaN/Inf in this data)
    return (uint16_t)(u >> 16);
}
__device__ __forceinline__ float bf16_to_f32(uint16_t v) {
    return __uint_as_float(((uint32_t)v) << 16);
}
__device__ __forceinline__ uint32_t pk_bf16(float lo, float hi) {
    float2 xy; xy.x = lo; xy.y = hi;
    __hip_bfloat162 b2 = __float22bfloat162_rn(xy);   // HW packed cvt on gfx950
    return *(uint32_t*)&b2;                            // .x in low 16 bits
}
// LDS-only fence: compiler barrier + drain LDS queue (no vmcnt wait).
#define LDS_FENCE() asm volatile("s_waitcnt lgkmcnt(0)" ::: "memory")

// ---------- K0 (R24): cvt_prep — one memory-bound pre-pass (unchanged) ------
__global__ __launch_bounds__(256) void cvt_prep(
    const float* __restrict__ q, const float* __restrict__ k, const float* __restrict__ v,
    const float* __restrict__ Wq, const float* __restrict__ Wk,
    const float* __restrict__ Wv, const float* __restrict__ Wo,
    const float* __restrict__ fsW1, const float* __restrict__ foW1,
    const float* __restrict__ fsW2, const float* __restrict__ foW2,
    ushort* __restrict__ qb, ushort* __restrict__ kb, ushort* __restrict__ vb,
    ushort* __restrict__ Wqt, ushort* __restrict__ Wkt,
    ushort* __restrict__ Wvt, ushort* __restrict__ Wot,
    uint4* __restrict__ bfrag1, uint4* __restrict__ bfrag2)
{
    __shared__ float tile[64][65];
    int t = threadIdx.x;
    int z = blockIdx.y, bx = blockIdx.x;

    if (z < 3) {
        const float* src = (z == 0) ? q : (z == 1) ? k : v;
        ushort* dst      = (z == 0) ? qb : (z == 1) ? kb : vb;
        size_t base = (size_t)bx * 2048 + (size_t)t * 8;
        float4 a = *(const float4*)&src[base];
        float4 b = *(const float4*)&src[base + 4];
        uint4 o;
        o.x = pk_bf16(a.x, a.y); o.y = pk_bf16(a.z, a.w);
        o.z = pk_bf16(b.x, b.y); o.w = pk_bf16(b.z, b.w);
        *(uint4*)&dst[base] = o;
        return;
    }

    if (bx < 256) {
        int mat = bx >> 6, tl = bx & 63;
        const float* Wf = (mat == 0) ? Wq : (mat == 1) ? Wk : (mat == 2) ? Wv : Wo;
        ushort* Wt      = (mat == 0) ? Wqt : (mat == 1) ? Wkt : (mat == 2) ? Wvt : Wot;
        int ki0 = (tl >> 3) * 64, ni0 = (tl & 7) * 64;
        {
            int r = t >> 2, cq = (t & 3) * 16;
            #pragma unroll
            for (int j = 0; j < 4; j++) {
                float4 v4 = *(const float4*)&Wf[(ki0 + r) * HID_ + ni0 + cq + j * 4];
                tile[r][cq + j * 4 + 0] = v4.x; tile[r][cq + j * 4 + 1] = v4.y;
                tile[r][cq + j * 4 + 2] = v4.z; tile[r][cq + j * 4 + 3] = v4.w;
            }
        }
        __syncthreads();
        {
            int n = t >> 2, kq = (t & 3) * 16;
            uint4 o0, o1;
            o0.x = pk_bf16(tile[kq + 0][n], tile[kq + 1][n]);
            o0.y = pk_bf16(tile[kq + 2][n], tile[kq + 3][n]);
            o0.z = pk_bf16(tile[kq + 4][n], tile[kq + 5][n]);
            o0.w = pk_bf16(tile[kq + 6][n], tile[kq + 7][n]);
            o1.x = pk_bf16(tile[kq + 8][n], tile[kq + 9][n]);
            o1.y = pk_bf16(tile[kq + 10][n], tile[kq + 11][n]);
            o1.z = pk_bf16(tile[kq + 12][n], tile[kq + 13][n]);
            o1.w = pk_bf16(tile[kq + 14][n], tile[kq + 15][n]);
            *(uint4*)&Wt[(ni0 + n) * HID_ + ki0 + kq] = o0;
            *(uint4*)&Wt[(ni0 + n) * HID_ + ki0 + kq + 8] = o1;
        }
        return;
    }

    if (bx == 256) {
        #pragma unroll
        for (int e = t; e < 512; e += 256) {
            int nt = e >> 6, lane = e & 63, l15 = lane & 15, qd = lane >> 4;
            int n = nt * 16 + l15;
            ushort vals[8];
            #pragma unroll
            for (int u = 0; u < 8; u++) {
                float x = 0.f;
                if (n < 64) {
                    if (qd == 0) x = fsW1[(16 + u) * 64 + n];
                    else if (qd == 1) x = fsW1[(8 + u) * 64 + n];
                } else {
                    int n2 = n - 64;
                    if (qd == 2) x = foW1[(16 + u) * 64 + n2];
                    else if (qd == 3) x = foW1[(8 + u) * 64 + n2];
                }
                vals[u] = f32_to_bf16(x);
            }
            uint4 pk;
            pk.x = (uint32_t)vals[0] | ((uint32_t)vals[1] << 16);
            pk.y = (uint32_t)vals[2] | ((uint32_t)vals[3] << 16);
            pk.z = (uint32_t)vals[4] | ((uint32_t)vals[5] << 16);
            pk.w = (uint32_t)vals[6] | ((uint32_t)vals[7] << 16);
            bfrag1[e] = pk;
        }
        {
            int e = t;
            int ks = e >> 6, lane = e & 63, l15 = lane & 15, qd = lane >> 4;
            ushort vals[8];
            #pragma unroll
            for (int u = 0; u < 8; u++) {
                float x = 0.f;
                if (l15 < 8) {
                    int k2 = ks * 32 + qd * 8 + u;
                    int c = ((k2 & 7) << 4) | (k2 >> 3);
                    x = LAM_ * ((c < 64) ? fsW2[c * 8 + l15] : foW2[(c - 64) * 8 + l15]);
                }
                vals[u] = f32_to_bf16(x);
            }
            uint4 pk;
            pk.x = (uint32_t)vals[0] | ((uint32_t)vals[1] << 16);
            pk.y = (uint32_t)vals[2] | ((uint32_t)vals[3] << 16);
            pk.z = (uint32_t)vals[4] | ((uint32_t)vals[5] << 16);
            pk.w = (uint32_t)vals[6] | ((uint32_t)vals[7] << 16);
            bfrag2[e] = pk;
        }
    }
}

// ---------- K1: QKV projection — R24 bf16 operands (unchanged) ----------
__global__ __launch_bounds__(256, 4) void proj_kernel(
    const ushort* __restrict__ qb, const ushort* __restrict__ kb, const ushort* __restrict__ vb,
    const ushort* __restrict__ Wqt, const ushort* __restrict__ Wkt, const ushort* __restrict__ Wvt,
    const float* __restrict__ bq, const float* __restrict__ bk, const float* __restrict__ bv,
    ushort* __restrict__ qh, ushort* __restrict__ kh, ushort* __restrict__ vh)
{
    int z = blockIdx.z;
    const ushort* X   = (z == 0) ? qb  : (z == 1) ? kb  : vb;
    const ushort* Wt  = (z == 0) ? Wqt : (z == 1) ? Wkt : Wvt;
    const float* bias = (z == 0) ? bq  : (z == 1) ? bk  : bv;
    ushort* out       = (z == 0) ? qh  : (z == 1) ? kh  : vh;
    float scale       = (z == 0) ? SCALE_ : 1.0f;

    int m0 = blockIdx.x * 128;
    int h  = blockIdx.y;
    int c0 = h * 64;

    __shared__ __align__(16) ushort Xs[2][128 * 40];
    __shared__ __align__(16) ushort Ws[2][64 * 40];

    int t = threadIdx.x;
    int wave = t >> 6, lane = t & 63;
    int l15 = lane & 15, qd = lane >> 4;

    // loader mapping
    int xr = t >> 1, xc = (t & 1) * 16;   // X: row 0..127, 16-col half
    int wn = t >> 2, wk = (t & 3) * 8;    // W^T: row n 0..63, 8-k chunk

    f32x4 acc0[4] = {}, acc1[4] = {};

    // prologue: prefetch tile 0
    uint4 xv0, xv1, wv;
    xv0 = *(const uint4*)&X[(size_t)(m0 + xr) * HID_ + xc];
    xv1 = *(const uint4*)&X[(size_t)(m0 + xr) * HID_ + xc + 8];
    wv  = *(const uint4*)&Wt[(size_t)(c0 + wn) * HID_ + wk];

    for (int k0 = 0; k0 < HID_; k0 += 32) {
        int buf = (k0 >> 5) & 1;
        // write prefetched regs -> LDS[buf] (pure copies)
        *(uint4*)&Xs[buf][xr * 40 + xc]     = xv0;
        *(uint4*)&Xs[buf][xr * 40 + xc + 8] = xv1;
        *(uint4*)&Ws[buf][wn * 40 + wk]     = wv;
        __syncthreads();   // single barrier: buf written; prior-iter reads of buf^1 done

        // issue tile k+1 loads (overlap with MFMA below)
        if (k0 + 32 < HID_) {
            int kn = k0 + 32;
            xv0 = *(const uint4*)&X[(size_t)(m0 + xr) * HID_ + kn + xc];
            xv1 = *(const uint4*)&X[(size_t)(m0 + xr) * HID_ + kn + xc + 8];
            wv  = *(const uint4*)&Wt[(size_t)(c0 + wn) * HID_ + kn + wk];
        }

        // MFMA: wave owns rows wave*32 .. +31 (two 16-row groups)
        bf16x8 af0 = *(const bf16x8*)&Xs[buf][(wave * 32 + l15) * 40 + qd * 8];
        bf16x8 af1 = *(const bf16x8*)&Xs[buf][(wave * 32 + 16 + l15) * 40 + qd * 8];
        #pragma unroll
        for (int nt = 0; nt < 4; nt++) {
            bf16x8 bf = *(const bf16x8*)&Ws[buf][(nt * 16 + l15) * 40 + qd * 8];
            acc0[nt] = __builtin_amdgcn_mfma_f32_16x16x32_bf16(af0, bf, acc0[nt], 0, 0, 0);
            acc1[nt] = __builtin_amdgcn_mfma_f32_16x16x32_bf16(af1, bf, acc1[nt], 0, 0, 0);
        }
    }

    // epilogue: bias + scale, bf16 store in head layout
    #pragma unroll
    for (int nt = 0; nt < 4; nt++) {
        float bb = bias[c0 + nt * 16 + l15];
        #pragma unroll
        for (int g = 0; g < 2; g++) {
            const f32x4& a = g ? acc1[nt] : acc0[nt];
            #pragma unroll
            for (int r = 0; r < 4; r++) {
                int m = m0 + wave * 32 + g * 16 + qd * 4 + r;
                int b_ = m >> 8, n_ = m & 255;
                float val = (a[r] + bb) * scale;
                out[(((b_ * H_ + h) * N_) + n_) * DK_ + nt * 16 + l15] = f32_to_bf16(val);
            }
        }
    }
}

// ---------- K3: pair-MLP via MFMA — R25 LDS-staged operands ----------
// R25: K3 issued ~27 VMEM reqs/thread: bfrag 12 (same 12 KB re-fetched by all
// 4096 blocks), feature rows 8, fsi/foi 4, hisbuf ~2, store 1. Now ONE
// coalesced cooperative stage (7 uint4/thread) of {sf[b] 8K, of[b] 8K,
// bfrag1 8K, bfrag2 4K} into the hbuf region (dead until after the stage is
// consumed); all fragment/feature reads become LDS reads. ~27 -> ~10 reqs.
// Numerics bit-identical.
#define HSTRIDE 136
__global__ __launch_bounds__(256, 3) void pair_bias_mfma(
    const float* __restrict__ sf, const float* __restrict__ of,
    const float* __restrict__ fsW1, const float* __restrict__ fsb1,
    const float* __restrict__ foW1, const float* __restrict__ fob1,
    const float* __restrict__ fsb2, const float* __restrict__ fob2,
    const uint4* __restrict__ bfrag1, const uint4* __restrict__ bfrag2,
    ushort* __restrict__ mlpb)
{
    __shared__ __align__(16) ushort hbuf[4][2][16 * HSTRIDE];   // 34,816 B
    __shared__ float hisbuf[128];
    __shared__ __align__(16) ushort mout[8 * 16 * 24];

    int i = blockIdx.x, b = blockIdx.y;
    int t = threadIdx.x;
    int wave = t >> 6, lane = t & 63;
    int l15 = lane & 15, qd = lane >> 4;

    // ---- Stage scratch overlays hbuf (consumed before hbuf's first write) --
    uint4* scratch = (uint4*)&hbuf[0][0][0];
    float* sfs  = (float*)scratch;             // [256][8] f32, 8 KB
    float* ofs  = (float*)(scratch + 512);     // [256][8] f32, 8 KB
    uint4* bf1s = scratch + 1024;              // 512 uint4, 8 KB
    uint4* bf2s = scratch + 1536;              // 256 uint4, 4 KB

    {
        const uint4* sfv = (const uint4*)(sf + (size_t)b * N_ * FEAT_);
        const uint4* ofv = (const uint4*)(of + (size_t)b * N_ * FEAT_);
        #pragma unroll
        for (int p = 0; p < 7; p++) {
            int u = t + p * 256;
            uint4 val;
            if (u < 512)        val = sfv[u];
            else if (u < 1024)  val = ofv[u - 512];
            else if (u < 1536)  val = bfrag1[u - 1024];
            else                val = bfrag2[u - 1536];
            scratch[u] = val;
        }
    }
    __syncthreads();   // stage visible

    // hisbuf: i-row features now from LDS; W1 rows 0..7 from global (small)
    if (t < 128) {
        int set = t >> 6, kk = t & 63;
        const float* W1 = set ? foW1 : fsW1;
        const float* fi = (set ? ofs : sfs) + i * FEAT_;
        float a = (set ? fob1 : fsb1)[kk];
        #pragma unroll
        for (int f = 0; f < FEAT_; f++) a += fi[f] * W1[f * 64 + kk];
        hisbuf[t] = a;
    }

    bf16x8 Bf1[8], Bf2[4];
    #pragma unroll
    for (int nt = 0; nt < 8; nt++) { U8 u; u.u = bf1s[nt * 64 + lane]; Bf1[nt] = u.h; }
    #pragma unroll
    for (int ks = 0; ks < 4; ks++) { U8 u; u.u = bf2s[ks * 64 + lane]; Bf2[ks] = u.h; }

    float fsi[8], foi[8];
    #pragma unroll
    for (int u = 0; u < 8; u++) { fsi[u] = sfs[i * FEAT_ + u]; foi[u] = ofs[i * FEAT_ + u]; }
    float b2l = LAM_ * (fsb2[l15 & 7] + fob2[l15 & 7]);

    // Pack ALL four A-fragments from LDS-staged feature rows.
    bf16x8 af[4];
    #pragma unroll
    for (int qt = 0; qt < 4; qt++) {
        int j = (wave * 4 + qt) * 16 + l15;
        const float* fr = ((qd < 2) ? sfs : ofs) + j * FEAT_;
        float4 f0 = *(const float4*)&fr[0];
        float4 f1 = *(const float4*)&fr[4];
        float vals[8] = {f0.x, f0.y, f0.z, f0.w, f1.x, f1.y, f1.z, f1.w};
        if ((qd & 1) == 0) {
            const float* fi = (qd < 2) ? fsi : foi;
            #pragma unroll
            for (int u = 0; u < 8; u++) vals[u] = fabsf(vals[u] - fi[u]);
        }
        U8 au;
        #pragma unroll
        for (int p = 0; p < 4; p++)
            ((uint32_t*)&au)[p] = pk_bf16(vals[2 * p], vals[2 * p + 1]);
        af[qt] = au.h;
    }

    __syncthreads();   // scratch fully consumed + hisbuf written -> hbuf reusable
    float hv[8];
    #pragma unroll
    for (int nt = 0; nt < 8; nt++) hv[nt] = hisbuf[nt * 16 + l15];

    // Pipeline prologue: S1(0) -> hb[0]
    {
        f32x4 S1[8];
        #pragma unroll
        for (int nt = 0; nt < 8; nt++) {
            f32x4 c0 = {hv[nt], hv[nt], hv[nt], hv[nt]};
            S1[nt] = __builtin_amdgcn_mfma_f32_16x16x32_bf16(af[0], Bf1[nt], c0, 0, 0, 0);
        }
        ushort* hb = &hbuf[wave][0][0];
        #pragma unroll
        for (int r = 0; r < 4; r++) {
            uint4 w;
            w.x = pk_bf16(fmaxf(S1[0][r], 0.f), fmaxf(S1[1][r], 0.f));
            w.y = pk_bf16(fmaxf(S1[2][r], 0.f), fmaxf(S1[3][r], 0.f));
            w.z = pk_bf16(fmaxf(S1[4][r], 0.f), fmaxf(S1[5][r], 0.f));
            w.w = pk_bf16(fmaxf(S1[6][r], 0.f), fmaxf(S1[7][r], 0.f));
            *(uint4*)&hb[(qd * 4 + r) * HSTRIDE + l15 * 8] = w;
        }
    }

    #pragma unroll
    for (int qt = 0; qt < 4; qt++) {
        ushort* hbC = &hbuf[wave][qt & 1][0];
        ushort* hbN = &hbuf[wave][(qt & 1) ^ 1][0];
        LDS_FENCE();               // hbC fully written (wave-local producer)

        // Next tile's S1: 8 independent MFMAs ahead of S2's dependent chain.
        f32x4 Sn[8];
        if (qt < 3) {
            #pragma unroll
            for (int nt = 0; nt < 8; nt++) {
                f32x4 c0 = {hv[nt], hv[nt], hv[nt], hv[nt]};
                Sn[nt] = __builtin_amdgcn_mfma_f32_16x16x32_bf16(af[qt + 1], Bf1[nt], c0, 0, 0, 0);
            }
        }

        // Second layer on current tile (4 dependent MFMAs)
        f32x4 S2 = {b2l, b2l, b2l, b2l};
        #pragma unroll
        for (int ks = 0; ks < 4; ks++) {
            bf16x8 a2 = *(const bf16x8*)&hbC[l15 * HSTRIDE + ks * 32 + qd * 8];
            S2 = __builtin_amdgcn_mfma_f32_16x16x32_bf16(a2, Bf2[ks], S2, 0, 0, 0);
        }

        // Direct LDS write of S2 into the permuted tile.
        if (l15 < 8) {
            int j0q = wave * 4 + qt;
            #pragma unroll
            for (int r = 0; r < 4; r++)
                mout[(l15 * 16 + qd * 4 + r) * 24 + j0q] = f32_to_bf16(S2[r]);
        }

        // ReLU-pack next tile into the other buffer.
        if (qt < 3) {
            #pragma unroll
            for (int r = 0; r < 4; r++) {
                uint4 w;
                w.x = pk_bf16(fmaxf(Sn[0][r], 0.f), fmaxf(Sn[1][r], 0.f));
                w.y = pk_bf16(fmaxf(Sn[2][r], 0.f), fmaxf(Sn[3][r], 0.f));
                w.z = pk_bf16(fmaxf(Sn[4][r], 0.f), fmaxf(Sn[5][r], 0.f));
                w.w = pk_bf16(fmaxf(Sn[6][r], 0.f), fmaxf(Sn[7][r], 0.f));
                *(uint4*)&hbN[(qd * 4 + r) * HSTRIDE + l15 * 8] = w;
            }
        }
    }

    __syncthreads();   // mout complete across all waves

    // ONE coalesced uint4 store per thread: 8 x 512B contiguous segments.
    {
        int h2 = t >> 5;                  // head 0..7
        int off = (t & 31) * 8;           // jlow*16 + jhigh0 within head row
        int jl = off >> 4, jh0 = off & 15;
        uint4 w = *(const uint4*)&mout[(h2 * 16 + jl) * 24 + jh0];
        *(uint4*)&mlpb[(((size_t)(b * H_ + h2) * N_ + i) * 256) + off] = w;
    }
}

// ---------- K4: MFMA attention (R22 de-requested bias phase, unchanged) -----
__global__ __launch_bounds__(256, 2) void attn_kernel(
    const ushort* __restrict__ qh, const ushort* __restrict__ kh,
    const ushort* __restrict__ vh, const float* __restrict__ tree,
    const ushort* __restrict__ mlpb, ushort* __restrict__ ctxb)
{
    __shared__ __align__(16) ushort bufKP[256 * 72];
    __shared__ __align__(16) ushort bufV[64 * 264];

    int blk = blockIdx.x;
    int bh = blk >> 2;
    int quarter = blk & 3;

    int t = threadIdx.x;
    int wave = t >> 6, lane = t & 63;
    int l15 = lane & 15, qd = lane >> 4;
    int i0w = quarter * 64 + wave * 16;

    const ushort* khb = kh + (size_t)bh * N_ * DK_;
    const ushort* vhb = vh + (size_t)bh * N_ * DK_;

    #pragma unroll
    for (int u = t; u < 2048; u += 256) {
        int j = u >> 3, seg = (u & 7) * 8;
        uint4 kv = *(const uint4*)&khb[j * DK_ + seg];
        *(uint4*)&bufKP[j * 72 + seg] = kv;
    }
    #pragma unroll
    for (int u = t; u < 1024; u += 256) {
        int rp = u & 127, d0 = (u >> 7) * 8;
        U8 v0, v1;
        v0.u = *(const uint4*)&vhb[(2 * rp) * DK_ + d0];
        v1.u = *(const uint4*)&vhb[(2 * rp + 1) * DK_ + d0];
        #pragma unroll
        for (int jj = 0; jj < 8; jj++) {
            uint32_t pk = (uint32_t)v0.s[jj] | ((uint32_t)v1.s[jj] << 16);
            *(uint32_t*)&bufV[(d0 + jj) * 264 + 2 * rp] = pk;
        }
    }
    __syncthreads();

    bf16x8 a0, a1;
    {
        size_t qb = ((size_t)bh * N_ + i0w + l15) * DK_;
        U8 t0, t1;
        t0.u = *(const uint4*)&qh[qb + qd * 8];
        t1.u = *(const uint4*)&qh[qb + 32 + qd * 8];
        a0 = t0.h; a1 = t1.h;
    }
    f32x4 S[16];
    #pragma unroll
    for (int nt = 0; nt < 16; nt++) {
        f32x4 acc = {};
        bf16x8 b0 = *(const bf16x8*)&bufKP[(nt * 16 + l15) * 72 + qd * 8];
        bf16x8 b1 = *(const bf16x8*)&bufKP[(nt * 16 + l15) * 72 + 32 + qd * 8];
        acc = __builtin_amdgcn_mfma_f32_16x16x32_bf16(a0, b0, acc, 0, 0, 0);
        acc = __builtin_amdgcn_mfma_f32_16x16x32_bf16(a1, b1, acc, 0, 0, 0);
        S[nt] = acc;
    }

    __syncthreads();   // K region of bufKP dead for ALL waves -> safe to reuse

    // mlpb, permuted layout: per row r, 16 bias values = 2 contiguous uint4
    {
        size_t rbase = (((size_t)bh * N_ + i0w + qd * 4) * 16 + l15) * 16;
        #pragma unroll
        for (int r = 0; r < 4; r++) {
            const ushort* mbp = mlpb + rbase + (size_t)r * 256;   // +1 row = +16*16
            U8 ma, mb2;
            ma.u  = *(const uint4*)&mbp[0];
            mb2.u = *(const uint4*)&mbp[8];
            #pragma unroll
            for (int nt = 0; nt < 8; nt++) S[nt][r]     += bf16_to_f32(ma.s[nt]);
            #pragma unroll
            for (int nt = 0; nt < 8; nt++) S[nt + 8][r] += bf16_to_f32(mb2.s[nt]);
        }
    }

    // tree: wave-local coalesced LDS bounce, f32, 2 halves of 128 cols.
    {
        float* tls = (float*)&bufKP[wave * 4608];
        #pragma unroll
        for (int half = 0; half < 2; half++) {
            #pragma unroll
            for (int f = 0; f < 8; f++) {
                int L = f * 64 + lane;
                int row = L >> 5, c4 = L & 31;     // 32 float4 per 128-col row
                float4 tv = *(const float4*)
                    &tree[((size_t)bh * N_ + i0w + row) * N_ + half * 128 + c4 * 4];
                *(float4*)&tls[row * 132 + c4 * 4] = tv;
            }
            LDS_FENCE();   // this wave's stage writes complete
            #pragma unroll
            for (int nt = 0; nt < 8; nt++) {
                #pragma unroll
                for (int r = 0; r < 4; r++)
                    S[half * 8 + nt][r] += tls[(qd * 4 + r) * 132 + nt * 16 + l15];
            }
            LDS_FENCE();   // half's reads complete before overwrite
        }
    }

    float mx[4], sm[4];
    #pragma unroll
    for (int r = 0; r < 4; r++) mx[r] = -1e30f;
    #pragma unroll
    for (int nt = 0; nt < 16; nt++)
        #pragma unroll
        for (int r = 0; r < 4; r++) mx[r] = fmaxf(mx[r], S[nt][r]);
    #pragma unroll
    for (int r = 0; r < 4; r++) {
        #pragma unroll
        for (int m = 1; m <= 8; m <<= 1) mx[r] = fmaxf(mx[r], __shfl_xor(mx[r], m));
    }
    #pragma unroll
    for (int r = 0; r < 4; r++) sm[r] = 0.f;
    #pragma unroll
    for (int nt = 0; nt < 16; nt++)
        #pragma unroll
        for (int r = 0; r < 4; r++) {
            float e = __expf(S[nt][r] - mx[r]);
            S[nt][r] = e;
            sm[r] += e;
        }
    #pragma unroll
    for (int r = 0; r < 4; r++) {
        #pragma unroll
        for (int m = 1; m <= 8; m <<= 1) sm[r] += __shfl_xor(sm[r], m);
        sm[r] = 1.0f / sm[r];
    }

    __syncthreads();   // tls reads drained; P region may now be written

    {
        uint32_t* Pw = (uint32_t*)&bufKP[wave * 16 * 264];
        #pragma unroll
        for (int nt = 0; nt < 16; nt++)
            #pragma unroll
            for (int r = 0; r < 4; r++) {
                float p = S[nt][r] * sm[r];
                float po = __shfl_xor(p, 1);
                uint32_t pk = (uint32_t)f32_to_bf16(p) | ((uint32_t)f32_to_bf16(po) << 16);
                if ((lane & 1) == 0)
                    Pw[(qd * 4 + r) * 132 + nt * 8 + (l15 >> 1)] = pk;
            }
    }
    __syncthreads();

    const ushort* Pw = &bufKP[wave * 16 * 264];
    f32x4 O[4] = {};
    #pragma unroll
    for (int ks = 0; ks < 8; ks++) {
        int j0 = ks * 32;
        bf16x8 pa = *(const bf16x8*)&Pw[l15 * 264 + j0 + qd * 8];
        #pragma unroll
        for (int ntd = 0; ntd < 4; ntd++) {
            bf16x8 vb = *(const bf16x8*)&bufV[(ntd * 16 + l15) * 264 + j0 + qd * 8];
            O[ntd] = __builtin_amdgcn_mfma_f32_16x16x32_bf16(pa, vb, O[ntd], 0, 0, 0);
        }
    }

    #pragma unroll
    for (int ntd = 0; ntd < 4; ntd++)
        #pragma unroll
        for (int r = 0; r < 4; r++)
            ctxb[((size_t)bh * N_ + i0w + qd * 4 + r) * DK_ + ntd * 16 + l15] =
                f32_to_bf16(O[ntd][r]);
}

// ---------- K5: output projection — R24 bf16 Wo^T loader (unchanged) --------
__global__ __launch_bounds__(256, 4) void outproj_kernel(
    const ushort* __restrict__ ctxb, const ushort* __restrict__ Wot,
    const float* __restrict__ bo, float* __restrict__ out)
{
    int m0 = blockIdx.x * 64;
    int c0 = blockIdx.y * 64;

    __shared__ __align__(16) ushort Xs[64 * 40];
    __shared__ __align__(16) ushort Ws[64 * 40];

    int t = threadIdx.x;
    int wave = t >> 6, lane = t & 63;
    int l15 = lane & 15, qd = lane >> 4;

    f32x4 acc[4] = {};

    for (int k0 = 0; k0 < HID_; k0 += 32) {
        __syncthreads();
        {
            int r = t >> 2, s8 = (t & 3) * 8;
            int m = m0 + r, b_ = m >> 8, n_ = m & 255;
            uint4 xv = *(const uint4*)&ctxb[(((b_ * H_ + (k0 >> 6)) * N_) + n_) * DK_ + (k0 & 63) + s8];
            *(uint4*)&Xs[r * 40 + s8] = xv;
        }
        {
            int wn = t >> 2, wk = (t & 3) * 8;
            uint4 wv = *(const uint4*)&Wot[(size_t)(c0 + wn) * HID_ + k0 + wk];
            *(uint4*)&Ws[wn * 40 + wk] = wv;
        }
        __syncthreads();
        bf16x8 af = *(const bf16x8*)&Xs[(wave * 16 + l15) * 40 + qd * 8];
        #pragma unroll
        for (int nt = 0; nt < 4; nt++) {
            bf16x8 bf = *(const bf16x8*)&Ws[(nt * 16 + l15) * 40 + qd * 8];
            acc[nt] = __builtin_amdgcn_mfma_f32_16x16x32_bf16(af, bf, acc[nt], 0, 0, 0);
        }
    }

    #pragma unroll
    for (int nt = 0; nt < 4; nt++) {
        float bb = bo[c0 + nt * 16 + l15];
        #pragma unroll
        for (int r = 0; r < 4; r++) {
            int m = m0 + wave * 16 + qd * 4 + r;
            out[m * HID_ + c0 + nt * 16 + l15] = acc[nt][r] + bb;
        }
    }
}

// ---------- launch ----------
extern "C" void kernel_launch(void* const* d_in, const int* in_sizes, int n_in,
                              void* d_out, int out_size, void* d_ws, size_t ws_size,
                              hipStream_t stream)
{
    const float* q    = (const float*)d_in[0];
    const float* k    = (const float*)d_in[1];
    const float* v    = (const float*)d_in[2];
    const float* tree = (const float*)d_in[3];
    const float* sf   = (const float*)d_in[4];
    const float* of   = (const float*)d_in[5];
    const float* Wq   = (const float*)d_in[6];
    const float* bq   = (const float*)d_in[7];
    const float* Wk   = (const float*)d_in[8];
    const float* bk   = (const float*)d_in[9];
    const float* Wv   = (const float*)d_in[10];
    const float* bv   = (const float*)d_in[11];
    const float* Wo   = (const float*)d_in[12];
    const float* bo   = (const float*)d_in[13];
    const float* fsW1 = (const float*)d_in[14];
    const float* fsb1 = (const float*)d_in[15];
    const float* fsW2 = (const float*)d_in[16];
    const float* fsb2 = (const float*)d_in[17];
    const float* foW1 = (const float*)d_in[18];
    const float* fob1 = (const float*)d_in[19];
    const float* foW2 = (const float*)d_in[20];
    const float* fob2 = (const float*)d_in[21];

    char* ws = (char*)d_ws;
    ushort* qh     = (ushort*)(ws + 0);            // 4,194,304
    ushort* kh     = (ushort*)(ws + 4194304);      // 4,194,304
    ushort* vh     = (ushort*)(ws + 8388608);      // 4,194,304
    ushort* ctxb   = (ushort*)(ws + 12582912);     // 4,194,304 (bf16)
    uint4*  bfrag1 = (uint4*)(ws + 16777216);      //     8,192
    uint4*  bfrag2 = (uint4*)(ws + 16785408);      //     4,096
    ushort* mlpb   = (ushort*)(ws + 23080960);     // 16,777,216 (permuted layout)
    ushort* qb     = (ushort*)(ws + 39858176);     // 4,194,304 (bf16 q)
    ushort* kb     = (ushort*)(ws + 44052480);     // 4,194,304
    ushort* vb     = (ushort*)(ws + 48246784);     // 4,194,304
    ushort* Wqt    = (ushort*)(ws + 52441088);     //   524,288 (bf16 W^T)
    ushort* Wkt    = (ushort*)(ws + 52965376);     //   524,288
    ushort* Wvt    = (ushort*)(ws + 53489664);     //   524,288
    ushort* Wot    = (ushort*)(ws + 54013952);     //   524,288

    cvt_prep<<<dim3(1024, 4), 256, 0, stream>>>(q, k, v, Wq, Wk, Wv, Wo,
                                                fsW1, foW1, fsW2, foW2,
                                                qb, kb, vb, Wqt, Wkt, Wvt, Wot,
                                                bfrag1, bfrag2);
    proj_kernel<<<dim3(32, 8, 3), 256, 0, stream>>>(qb, kb, vb, Wqt, Wkt, Wvt,
                                                    bq, bk, bv, qh, kh, vh);
    pair_bias_mfma<<<dim3(N_, B_), 256, 0, stream>>>(sf, of, fsW1, fsb1, foW1, fob1,
                                                     fsb2, fob2, bfrag1, bfrag2, mlpb);
    attn_kernel<<<512, 256, 0, stream>>>(qh, kh, vh, tree, mlpb, ctxb);
    outproj_kernel<<<dim3(64, 8), 256, 0, stream>>>(ctxb, Wot, bo, (float*)d_out);
}

// Round 15
// 209.336 us; speedup vs baseline: 1.0120x; 1.0120x over previous
//
#include <hip/hip_runtime.h>
#include <hip/hip_bf16.h>
#include <stdint.h>

// Problem constants
#define B_    16
#define N_    256
#define HID_  512
#define H_    8
#define DK_   64
#define FEAT_ 8
#define MLPH_ 64
#define LAM_  0.1f
#define SCALE_ 0.125f   // DK^-0.5

typedef short bf16x8 __attribute__((ext_vector_type(8)));
typedef float f32x4  __attribute__((ext_vector_type(4)));

union U8 { uint4 u; bf16x8 h; ushort s[8]; };

__device__ __forceinline__ uint16_t f32_to_bf16(float x) {
    uint32_t u = __float_as_uint(x);
    u += 0x7fffu + ((u >> 16) & 1u);      // RNE (no NaN/Inf in this data)
    return (uint16_t)(u >> 16);
}
__device__ __forceinline__ float bf16_to_f32(uint16_t v) {
    return __uint_as_float(((uint32_t)v) << 16);
}
__device__ __forceinline__ uint32_t pk_bf16(float lo, float hi) {
    float2 xy; xy.x = lo; xy.y = hi;
    __hip_bfloat162 b2 = __float22bfloat162_rn(xy);   // HW packed cvt on gfx950
    return *(uint32_t*)&b2;                            // .x in low 16 bits
}
// LDS-only fence: compiler barrier + drain LDS queue (no vmcnt wait).
#define LDS_FENCE() asm volatile("s_waitcnt lgkmcnt(0)" ::: "memory")

// ---------- K0 (R24): cvt_prep — one memory-bound pre-pass (unchanged) ------
__global__ __launch_bounds__(256) void cvt_prep(
    const float* __restrict__ q, const float* __restrict__ k, const float* __restrict__ v,
    const float* __restrict__ Wq, const float* __restrict__ Wk,
    const float* __restrict__ Wv, const float* __restrict__ Wo,
    const float* __restrict__ fsW1, const float* __restrict__ foW1,
    const float* __restrict__ fsW2, const float* __restrict__ foW2,
    ushort* __restrict__ qb, ushort* __restrict__ kb, ushort* __restrict__ vb,
    ushort* __restrict__ Wqt, ushort* __restrict__ Wkt,
    ushort* __restrict__ Wvt, ushort* __restrict__ Wot,
    uint4* __restrict__ bfrag1, uint4* __restrict__ bfrag2)
{
    __shared__ float tile[64][65];
    int t = threadIdx.x;
    int z = blockIdx.y, bx = blockIdx.x;

    if (z < 3) {
        const float* src = (z == 0) ? q : (z == 1) ? k : v;
        ushort* dst      = (z == 0) ? qb : (z == 1) ? kb : vb;
        size_t base = (size_t)bx * 2048 + (size_t)t * 8;
        float4 a = *(const float4*)&src[base];
        float4 b = *(const float4*)&src[base + 4];
        uint4 o;
        o.x = pk_bf16(a.x, a.y); o.y = pk_bf16(a.z, a.w);
        o.z = pk_bf16(b.x, b.y); o.w = pk_bf16(b.z, b.w);
        *(uint4*)&dst[base] = o;
        return;
    }

    if (bx < 256) {
        int mat = bx >> 6, tl = bx & 63;
        const float* Wf = (mat == 0) ? Wq : (mat == 1) ? Wk : (mat == 2) ? Wv : Wo;
        ushort* Wt      = (mat == 0) ? Wqt : (mat == 1) ? Wkt : (mat == 2) ? Wvt : Wot;
        int ki0 = (tl >> 3) * 64, ni0 = (tl & 7) * 64;
        {
            int r = t >> 2, cq = (t & 3) * 16;
            #pragma unroll
            for (int j = 0; j < 4; j++) {
                float4 v4 = *(const float4*)&Wf[(ki0 + r) * HID_ + ni0 + cq + j * 4];
                tile[r][cq + j * 4 + 0] = v4.x; tile[r][cq + j * 4 + 1] = v4.y;
                tile[r][cq + j * 4 + 2] = v4.z; tile[r][cq + j * 4 + 3] = v4.w;
            }
        }
        __syncthreads();
        {
            int n = t >> 2, kq = (t & 3) * 16;
            uint4 o0, o1;
            o0.x = pk_bf16(tile[kq + 0][n], tile[kq + 1][n]);
            o0.y = pk_bf16(tile[kq + 2][n], tile[kq + 3][n]);
            o0.z = pk_bf16(tile[kq + 4][n], tile[kq + 5][n]);
            o0.w = pk_bf16(tile[kq + 6][n], tile[kq + 7][n]);
            o1.x = pk_bf16(tile[kq + 8][n], tile[kq + 9][n]);
            o1.y = pk_bf16(tile[kq + 10][n], tile[kq + 11][n]);
            o1.z = pk_bf16(tile[kq + 12][n], tile[kq + 13][n]);
            o1.w = pk_bf16(tile[kq + 14][n], tile[kq + 15][n]);
            *(uint4*)&Wt[(ni0 + n) * HID_ + ki0 + kq] = o0;
            *(uint4*)&Wt[(ni0 + n) * HID_ + ki0 + kq + 8] = o1;
        }
        return;
    }

    if (bx == 256) {
        #pragma unroll
        for (int e = t; e < 512; e += 256) {
            int nt = e >> 6, lane = e & 63, l15 = lane & 15, qd = lane >> 4;
            int n = nt * 16 + l15;
            ushort vals[8];
            #pragma unroll
            for (int u = 0; u < 8; u++) {
                float x = 0.f;
                if (n < 64) {
                    if (qd == 0) x = fsW1[(16 + u) * 64 + n];
                    else if (qd == 1) x = fsW1[(8 + u) * 64 + n];
                } else {
                    int n2 = n - 64;
                    if (qd == 2) x = foW1[(16 + u) * 64 + n2];
                    else if (qd == 3) x = foW1[(8 + u) * 64 + n2];
                }
                vals[u] = f32_to_bf16(x);
            }
            uint4 pk;
            pk.x = (uint32_t)vals[0] | ((uint32_t)vals[1] << 16);
            pk.y = (uint32_t)vals[2] | ((uint32_t)vals[3] << 16);
            pk.z = (uint32_t)vals[4] | ((uint32_t)vals[5] << 16);
            pk.w = (uint32_t)vals[6] | ((uint32_t)vals[7] << 16);
            bfrag1[e] = pk;
        }
        {
            int e = t;
            int ks = e >> 6, lane = e & 63, l15 = lane & 15, qd = lane >> 4;
            ushort vals[8];
            #pragma unroll
            for (int u = 0; u < 8; u++) {
                float x = 0.f;
                if (l15 < 8) {
                    int k2 = ks * 32 + qd * 8 + u;
                    int c = ((k2 & 7) << 4) | (k2 >> 3);
                    x = LAM_ * ((c < 64) ? fsW2[c * 8 + l15] : foW2[(c - 64) * 8 + l15]);
                }
                vals[u] = f32_to_bf16(x);
            }
            uint4 pk;
            pk.x = (uint32_t)vals[0] | ((uint32_t)vals[1] << 16);
            pk.y = (uint32_t)vals[2] | ((uint32_t)vals[3] << 16);
            pk.z = (uint32_t)vals[4] | ((uint32_t)vals[5] << 16);
            pk.w = (uint32_t)vals[6] | ((uint32_t)vals[7] << 16);
            bfrag2[e] = pk;
        }
    }
}

// ---------- K1: QKV projection — R24 bf16 operands (unchanged) ----------
__global__ __launch_bounds__(256, 4) void proj_kernel(
    const ushort* __restrict__ qb, const ushort* __restrict__ kb, const ushort* __restrict__ vb,
    const ushort* __restrict__ Wqt, const ushort* __restrict__ Wkt, const ushort* __restrict__ Wvt,
    const float* __restrict__ bq, const float* __restrict__ bk, const float* __restrict__ bv,
    ushort* __restrict__ qh, ushort* __restrict__ kh, ushort* __restrict__ vh)
{
    int z = blockIdx.z;
    const ushort* X   = (z == 0) ? qb  : (z == 1) ? kb  : vb;
    const ushort* Wt  = (z == 0) ? Wqt : (z == 1) ? Wkt : Wvt;
    const float* bias = (z == 0) ? bq  : (z == 1) ? bk  : bv;
    ushort* out       = (z == 0) ? qh  : (z == 1) ? kh  : vh;
    float scale       = (z == 0) ? SCALE_ : 1.0f;

    int m0 = blockIdx.x * 128;
    int h  = blockIdx.y;
    int c0 = h * 64;

    __shared__ __align__(16) ushort Xs[2][128 * 40];
    __shared__ __align__(16) ushort Ws[2][64 * 40];

    int t = threadIdx.x;
    int wave = t >> 6, lane = t & 63;
    int l15 = lane & 15, qd = lane >> 4;

    // loader mapping
    int xr = t >> 1, xc = (t & 1) * 16;   // X: row 0..127, 16-col half
    int wn = t >> 2, wk = (t & 3) * 8;    // W^T: row n 0..63, 8-k chunk

    f32x4 acc0[4] = {}, acc1[4] = {};

    // prologue: prefetch tile 0
    uint4 xv0, xv1, wv;
    xv0 = *(const uint4*)&X[(size_t)(m0 + xr) * HID_ + xc];
    xv1 = *(const uint4*)&X[(size_t)(m0 + xr) * HID_ + xc + 8];
    wv  = *(const uint4*)&Wt[(size_t)(c0 + wn) * HID_ + wk];

    for (int k0 = 0; k0 < HID_; k0 += 32) {
        int buf = (k0 >> 5) & 1;
        // write prefetched regs -> LDS[buf] (pure copies)
        *(uint4*)&Xs[buf][xr * 40 + xc]     = xv0;
        *(uint4*)&Xs[buf][xr * 40 + xc + 8] = xv1;
        *(uint4*)&Ws[buf][wn * 40 + wk]     = wv;
        __syncthreads();   // single barrier: buf written; prior-iter reads of buf^1 done

        // issue tile k+1 loads (overlap with MFMA below)
        if (k0 + 32 < HID_) {
            int kn = k0 + 32;
            xv0 = *(const uint4*)&X[(size_t)(m0 + xr) * HID_ + kn + xc];
            xv1 = *(const uint4*)&X[(size_t)(m0 + xr) * HID_ + kn + xc + 8];
            wv  = *(const uint4*)&Wt[(size_t)(c0 + wn) * HID_ + kn + wk];
        }

        // MFMA: wave owns rows wave*32 .. +31 (two 16-row groups)
        bf16x8 af0 = *(const bf16x8*)&Xs[buf][(wave * 32 + l15) * 40 + qd * 8];
        bf16x8 af1 = *(const bf16x8*)&Xs[buf][(wave * 32 + 16 + l15) * 40 + qd * 8];
        #pragma unroll
        for (int nt = 0; nt < 4; nt++) {
            bf16x8 bf = *(const bf16x8*)&Ws[buf][(nt * 16 + l15) * 40 + qd * 8];
            acc0[nt] = __builtin_amdgcn_mfma_f32_16x16x32_bf16(af0, bf, acc0[nt], 0, 0, 0);
            acc1[nt] = __builtin_amdgcn_mfma_f32_16x16x32_bf16(af1, bf, acc1[nt], 0, 0, 0);
        }
    }

    // epilogue: bias + scale, bf16 store in head layout
    #pragma unroll
    for (int nt = 0; nt < 4; nt++) {
        float bb = bias[c0 + nt * 16 + l15];
        #pragma unroll
        for (int g = 0; g < 2; g++) {
            const f32x4& a = g ? acc1[nt] : acc0[nt];
            #pragma unroll
            for (int r = 0; r < 4; r++) {
                int m = m0 + wave * 32 + g * 16 + qd * 4 + r;
                int b_ = m >> 8, n_ = m & 255;
                float val = (a[r] + bb) * scale;
                out[(((b_ * H_ + h) * N_) + n_) * DK_ + nt * 16 + l15] = f32_to_bf16(val);
            }
        }
    }
}

// ---------- K3: pair-MLP — R26 multi-i batching (4 rows/block) ----------
// R25 (operand LDS-stage) was neutral: bfrag/feature reads were L2-broadcast
// already. New model: K3 = per-block FIXED cost x 4096 blocks. R26: grid
// (64,16) = 1024 blocks, each does 4 i-rows. Feature stage (16 KB, persistent)
// + bfrag reg loads + launch cost amortized 4x. All-4 hisbufs precomputed (2
// prologue barriers). Per-i body = round-0's verified single-buffer qt loop
// (R13 Sn-pipeline dropped: measured neutral) + R23 coalesced mout store.
#define HSTRIDE 136
__global__ __launch_bounds__(256, 3) void pair_bias_mfma(
    const float* __restrict__ sf, const float* __restrict__ of,
    const float* __restrict__ fsW1, const float* __restrict__ fsb1,
    const float* __restrict__ foW1, const float* __restrict__ fob1,
    const float* __restrict__ fsb2, const float* __restrict__ fob2,
    const uint4* __restrict__ bfrag1, const uint4* __restrict__ bfrag2,
    ushort* __restrict__ mlpb)
{
    __shared__ __align__(16) float feat[2 * N_ * FEAT_];        // 16,384 B (persistent)
    __shared__ __align__(16) ushort hbuf[4][16 * HSTRIDE];      // 17,408 B (per-wave)
    __shared__ float hisbuf[4][128];                            //  2,048 B
    __shared__ __align__(16) ushort mout[8 * 16 * 24];          //  6,144 B

    int i0 = blockIdx.x * 4, b = blockIdx.y;
    int t = threadIdx.x;
    int wave = t >> 6, lane = t & 63;
    int l15 = lane & 15, qd = lane >> 4;

    // ---- Persistent feature stage: sf[b] + of[b], 4 uint4/thread ----
    {
        uint4* featv = (uint4*)feat;
        const uint4* sfv = (const uint4*)(sf + (size_t)b * N_ * FEAT_);
        const uint4* ofv = (const uint4*)(of + (size_t)b * N_ * FEAT_);
        #pragma unroll
        for (int p = 0; p < 4; p++) {
            int u = t + p * 256;
            featv[u] = (u < 512) ? sfv[u] : ofv[u - 512];
        }
    }
    const float* sfs = feat;
    const float* ofs = feat + N_ * FEAT_;

    bf16x8 Bf1[8], Bf2[4];
    #pragma unroll
    for (int nt = 0; nt < 8; nt++) { U8 u; u.u = bfrag1[nt * 64 + lane]; Bf1[nt] = u.h; }
    #pragma unroll
    for (int ks = 0; ks < 4; ks++) { U8 u; u.u = bfrag2[ks * 64 + lane]; Bf2[ks] = u.h; }
    float b2l = LAM_ * (fsb2[l15 & 7] + fob2[l15 & 7]);

    __syncthreads();   // feature stage visible

    // ---- All 4 hisbufs up front ----
    if (t < 128) {
        int set = t >> 6, kk = t & 63;
        const float* W1 = set ? foW1 : fsW1;
        float bb = (set ? fob1 : fsb1)[kk];
        #pragma unroll
        for (int ii = 0; ii < 4; ii++) {
            const float* fi = (set ? ofs : sfs) + (i0 + ii) * FEAT_;
            float a = bb;
            #pragma unroll
            for (int f = 0; f < FEAT_; f++) a += fi[f] * W1[f * 64 + kk];
            hisbuf[ii][t] = a;
        }
    }
    __syncthreads();   // hisbufs ready

    ushort* hb = &hbuf[wave][0];

    for (int ii = 0; ii < 4; ii++) {
        int i = i0 + ii;

        float fsi[8], foi[8];
        #pragma unroll
        for (int u = 0; u < 8; u++) { fsi[u] = sfs[i * FEAT_ + u]; foi[u] = ofs[i * FEAT_ + u]; }

        float hv[8];
        #pragma unroll
        for (int nt = 0; nt < 8; nt++) hv[nt] = hisbuf[ii][nt * 16 + l15];

        // A-fragments for this i (j rows shared; |.| uses row i)
        bf16x8 af[4];
        #pragma unroll
        for (int qt = 0; qt < 4; qt++) {
            int j = (wave * 4 + qt) * 16 + l15;
            const float* fr = ((qd < 2) ? sfs : ofs) + j * FEAT_;
            float4 f0 = *(const float4*)&fr[0];
            float4 f1 = *(const float4*)&fr[4];
            float vals[8] = {f0.x, f0.y, f0.z, f0.w, f1.x, f1.y, f1.z, f1.w};
            if ((qd & 1) == 0) {
                const float* fi = (qd < 2) ? fsi : foi;
                #pragma unroll
                for (int u = 0; u < 8; u++) vals[u] = fabsf(vals[u] - fi[u]);
            }
            U8 au;
            #pragma unroll
            for (int p = 0; p < 4; p++)
                ((uint32_t*)&au)[p] = pk_bf16(vals[2 * p], vals[2 * p + 1]);
            af[qt] = au.h;
        }

        #pragma unroll
        for (int qt = 0; qt < 4; qt++) {
            f32x4 S1[8];
            #pragma unroll
            for (int nt = 0; nt < 8; nt++) {
                f32x4 c0 = {hv[nt], hv[nt], hv[nt], hv[nt]};
                S1[nt] = __builtin_amdgcn_mfma_f32_16x16x32_bf16(af[qt], Bf1[nt], c0, 0, 0, 0);
            }
            #pragma unroll
            for (int r = 0; r < 4; r++) {
                uint4 w;
                w.x = pk_bf16(fmaxf(S1[0][r], 0.f), fmaxf(S1[1][r], 0.f));
                w.y = pk_bf16(fmaxf(S1[2][r], 0.f), fmaxf(S1[3][r], 0.f));
                w.z = pk_bf16(fmaxf(S1[4][r], 0.f), fmaxf(S1[5][r], 0.f));
                w.w = pk_bf16(fmaxf(S1[6][r], 0.f), fmaxf(S1[7][r], 0.f));
                *(uint4*)&hb[(qd * 4 + r) * HSTRIDE + l15 * 8] = w;
            }
            LDS_FENCE();   // wave-local: hb writes done before reads

            f32x4 S2 = {b2l, b2l, b2l, b2l};
            #pragma unroll
            for (int ks = 0; ks < 4; ks++) {
                bf16x8 a2 = *(const bf16x8*)&hb[l15 * HSTRIDE + ks * 32 + qd * 8];
                S2 = __builtin_amdgcn_mfma_f32_16x16x32_bf16(a2, Bf2[ks], S2, 0, 0, 0);
            }
            LDS_FENCE();   // hb reads done before next qt overwrites

            if (l15 < 8) {
                int j0q = wave * 4 + qt;
                #pragma unroll
                for (int r = 0; r < 4; r++)
                    mout[(l15 * 16 + qd * 4 + r) * 24 + j0q] = f32_to_bf16(S2[r]);
            }
        }

        __syncthreads();   // mout complete across all waves

        {
            int h2 = t >> 5;                  // head 0..7
            int off = (t & 31) * 8;
            int jl = off >> 4, jh0 = off & 15;
            uint4 w = *(const uint4*)&mout[(h2 * 16 + jl) * 24 + jh0];
            *(uint4*)&mlpb[(((size_t)(b * H_ + h2) * N_ + i) * 256) + off] = w;
        }

        __syncthreads();   // stores' LDS reads drained before next i's mout writes
    }
}

// ---------- K4: MFMA attention — R26 coalesced O-store ----------
__global__ __launch_bounds__(256, 2) void attn_kernel(
    const ushort* __restrict__ qh, const ushort* __restrict__ kh,
    const ushort* __restrict__ vh, const float* __restrict__ tree,
    const ushort* __restrict__ mlpb, ushort* __restrict__ ctxb)
{
    __shared__ __align__(16) ushort bufKP[256 * 72];
    __shared__ __align__(16) ushort bufV[64 * 264];

    int blk = blockIdx.x;
    int bh = blk >> 2;
    int quarter = blk & 3;

    int t = threadIdx.x;
    int wave = t >> 6, lane = t & 63;
    int l15 = lane & 15, qd = lane >> 4;
    int i0w = quarter * 64 + wave * 16;

    const ushort* khb = kh + (size_t)bh * N_ * DK_;
    const ushort* vhb = vh + (size_t)bh * N_ * DK_;

    #pragma unroll
    for (int u = t; u < 2048; u += 256) {
        int j = u >> 3, seg = (u & 7) * 8;
        uint4 kv = *(const uint4*)&khb[j * DK_ + seg];
        *(uint4*)&bufKP[j * 72 + seg] = kv;
    }
    #pragma unroll
    for (int u = t; u < 1024; u += 256) {
        int rp = u & 127, d0 = (u >> 7) * 8;
        U8 v0, v1;
        v0.u = *(const uint4*)&vhb[(2 * rp) * DK_ + d0];
        v1.u = *(const uint4*)&vhb[(2 * rp + 1) * DK_ + d0];
        #pragma unroll
        for (int jj = 0; jj < 8; jj++) {
            uint32_t pk = (uint32_t)v0.s[jj] | ((uint32_t)v1.s[jj] << 16);
            *(uint32_t*)&bufV[(d0 + jj) * 264 + 2 * rp] = pk;
        }
    }
    __syncthreads();

    bf16x8 a0, a1;
    {
        size_t qb = ((size_t)bh * N_ + i0w + l15) * DK_;
        U8 t0, t1;
        t0.u = *(const uint4*)&qh[qb + qd * 8];
        t1.u = *(const uint4*)&qh[qb + 32 + qd * 8];
        a0 = t0.h; a1 = t1.h;
    }
    f32x4 S[16];
    #pragma unroll
    for (int nt = 0; nt < 16; nt++) {
        f32x4 acc = {};
        bf16x8 b0 = *(const bf16x8*)&bufKP[(nt * 16 + l15) * 72 + qd * 8];
        bf16x8 b1 = *(const bf16x8*)&bufKP[(nt * 16 + l15) * 72 + 32 + qd * 8];
        acc = __builtin_amdgcn_mfma_f32_16x16x32_bf16(a0, b0, acc, 0, 0, 0);
        acc = __builtin_amdgcn_mfma_f32_16x16x32_bf16(a1, b1, acc, 0, 0, 0);
        S[nt] = acc;
    }

    __syncthreads();   // K region of bufKP dead for ALL waves -> safe to reuse

    // mlpb, permuted layout: per row r, 16 bias values = 2 contiguous uint4
    {
        size_t rbase = (((size_t)bh * N_ + i0w + qd * 4) * 16 + l15) * 16;
        #pragma unroll
        for (int r = 0; r < 4; r++) {
            const ushort* mbp = mlpb + rbase + (size_t)r * 256;   // +1 row = +16*16
            U8 ma, mb2;
            ma.u  = *(const uint4*)&mbp[0];
            mb2.u = *(const uint4*)&mbp[8];
            #pragma unroll
            for (int nt = 0; nt < 8; nt++) S[nt][r]     += bf16_to_f32(ma.s[nt]);
            #pragma unroll
            for (int nt = 0; nt < 8; nt++) S[nt + 8][r] += bf16_to_f32(mb2.s[nt]);
        }
    }

    // tree: wave-local coalesced LDS bounce, f32, 2 halves of 128 cols.
    {
        float* tls = (float*)&bufKP[wave * 4608];
        #pragma unroll
        for (int half = 0; half < 2; half++) {
            #pragma unroll
            for (int f = 0; f < 8; f++) {
                int L = f * 64 + lane;
                int row = L >> 5, c4 = L & 31;     // 32 float4 per 128-col row
                float4 tv = *(const float4*)
                    &tree[((size_t)bh * N_ + i0w + row) * N_ + half * 128 + c4 * 4];
                *(float4*)&tls[row * 132 + c4 * 4] = tv;
            }
            LDS_FENCE();   // this wave's stage writes complete
            #pragma unroll
            for (int nt = 0; nt < 8; nt++) {
                #pragma unroll
                for (int r = 0; r < 4; r++)
                    S[half * 8 + nt][r] += tls[(qd * 4 + r) * 132 + nt * 16 + l15];
            }
            LDS_FENCE();   // half's reads complete before overwrite
        }
    }

    float mx[4], sm[4];
    #pragma unroll
    for (int r = 0; r < 4; r++) mx[r] = -1e30f;
    #pragma unroll
    for (int nt = 0; nt < 16; nt++)
        #pragma unroll
        for (int r = 0; r < 4; r++) mx[r] = fmaxf(mx[r], S[nt][r]);
    #pragma unroll
    for (int r = 0; r < 4; r++) {
        #pragma unroll
        for (int m = 1; m <= 8; m <<= 1) mx[r] = fmaxf(mx[r], __shfl_xor(mx[r], m));
    }
    #pragma unroll
    for (int r = 0; r < 4; r++) sm[r] = 0.f;
    #pragma unroll
    for (int nt = 0; nt < 16; nt++)
        #pragma unroll
        for (int r = 0; r < 4; r++) {
            float e = __expf(S[nt][r] - mx[r]);
            S[nt][r] = e;
            sm[r] += e;
        }
    #pragma unroll
    for (int r = 0; r < 4; r++) {
        #pragma unroll
        for (int m = 1; m <= 8; m <<= 1) sm[r] += __shfl_xor(sm[r], m);
        sm[r] = 1.0f / sm[r];
    }

    __syncthreads();   // tls reads drained; P region may now be written

    {
        uint32_t* Pw = (uint32_t*)&bufKP[wave * 16 * 264];
        #pragma unroll
        for (int nt = 0; nt < 16; nt++)
            #pragma unroll
            for (int r = 0; r < 4; r++) {
                float p = S[nt][r] * sm[r];
                float po = __shfl_xor(p, 1);
                uint32_t pk = (uint32_t)f32_to_bf16(p) | ((uint32_t)f32_to_bf16(po) << 16);
                if ((lane & 1) == 0)
                    Pw[(qd * 4 + r) * 132 + nt * 8 + (l15 >> 1)] = pk;
            }
    }
    __syncthreads();

    const ushort* Pw = &bufKP[wave * 16 * 264];
    f32x4 O[4] = {};
    #pragma unroll
    for (int ks = 0; ks < 8; ks++) {
        int j0 = ks * 32;
        bf16x8 pa = *(const bf16x8*)&Pw[l15 * 264 + j0 + qd * 8];
        #pragma unroll
        for (int ntd = 0; ntd < 4; ntd++) {
            bf16x8 vb = *(const bf16x8*)&bufV[(ntd * 16 + l15) * 264 + j0 + qd * 8];
            O[ntd] = __builtin_amdgcn_mfma_f32_16x16x32_bf16(pa, vb, O[ntd], 0, 0, 0);
        }
    }

    // R26: O-store via LDS bounce -> 2 fully-coalesced uint4/thread (one
    // contiguous 8 KB ctxb run per block). bufV is dead after the barrier.
    __syncthreads();   // all waves done reading bufV
    {
        ushort* ob = bufV;   // [64 rows][stride 72]
        #pragma unroll
        for (int ntd = 0; ntd < 4; ntd++)
            #pragma unroll
            for (int r = 0; r < 4; r++)
                ob[(wave * 16 + qd * 4 + r) * 72 + ntd * 16 + l15] = f32_to_bf16(O[ntd][r]);
    }
    __syncthreads();
    {
        int row = t >> 2, cc = (t & 3) * 16;
        uint4 w0 = *(const uint4*)&bufV[row * 72 + cc];
        uint4 w1 = *(const uint4*)&bufV[row * 72 + cc + 8];
        size_t dst = ((size_t)bh * N_ + quarter * 64 + row) * DK_ + cc;
        *(uint4*)&ctxb[dst]     = w0;
        *(uint4*)&ctxb[dst + 8] = w1;
    }
}

// ---------- K5: output projection — R24 bf16 Wo^T loader (unchanged) --------
__global__ __launch_bounds__(256, 4) void outproj_kernel(
    const ushort* __restrict__ ctxb, const ushort* __restrict__ Wot,
    const float* __restrict__ bo, float* __restrict__ out)
{
    int m0 = blockIdx.x * 64;
    int c0 = blockIdx.y * 64;

    __shared__ __align__(16) ushort Xs[64 * 40];
    __shared__ __align__(16) ushort Ws[64 * 40];

    int t = threadIdx.x;
    int wave = t >> 6, lane = t & 63;
    int l15 = lane & 15, qd = lane >> 4;

    f32x4 acc[4] = {};

    for (int k0 = 0; k0 < HID_; k0 += 32) {
        __syncthreads();
        {
            int r = t >> 2, s8 = (t & 3) * 8;
            int m = m0 + r, b_ = m >> 8, n_ = m & 255;
            uint4 xv = *(const uint4*)&ctxb[(((b_ * H_ + (k0 >> 6)) * N_) + n_) * DK_ + (k0 & 63) + s8];
            *(uint4*)&Xs[r * 40 + s8] = xv;
        }
        {
            int wn = t >> 2, wk = (t & 3) * 8;
            uint4 wv = *(const uint4*)&Wot[(size_t)(c0 + wn) * HID_ + k0 + wk];
            *(uint4*)&Ws[wn * 40 + wk] = wv;
        }
        __syncthreads();
        bf16x8 af = *(const bf16x8*)&Xs[(wave * 16 + l15) * 40 + qd * 8];
        #pragma unroll
        for (int nt = 0; nt < 4; nt++) {
            bf16x8 bf = *(const bf16x8*)&Ws[(nt * 16 + l15) * 40 + qd * 8];
            acc[nt] = __builtin_amdgcn_mfma_f32_16x16x32_bf16(af, bf, acc[nt], 0, 0, 0);
        }
    }

    #pragma unroll
    for (int nt = 0; nt < 4; nt++) {
        float bb = bo[c0 + nt * 16 + l15];
        #pragma unroll
        for (int r = 0; r < 4; r++) {
            int m = m0 + wave * 16 + qd * 4 + r;
            out[m * HID_ + c0 + nt * 16 + l15] = acc[nt][r] + bb;
        }
    }
}

// ---------- launch ----------
extern "C" void kernel_launch(void* const* d_in, const int* in_sizes, int n_in,
                              void* d_out, int out_size, void* d_ws, size_t ws_size,
                              hipStream_t stream)
{
    const float* q    = (const float*)d_in[0];
    const float* k    = (const float*)d_in[1];
    const float* v    = (const float*)d_in[2];
    const float* tree = (const float*)d_in[3];
    const float* sf   = (const float*)d_in[4];
    const float* of   = (const float*)d_in[5];
    const float* Wq   = (const float*)d_in[6];
    const float* bq   = (const float*)d_in[7];
    const float* Wk   = (const float*)d_in[8];
    const float* bk   = (const float*)d_in[9];
    const float* Wv   = (const float*)d_in[10];
    const float* bv   = (const float*)d_in[11];
    const float* Wo   = (const float*)d_in[12];
    const float* bo   = (const float*)d_in[13];
    const float* fsW1 = (const float*)d_in[14];
    const float* fsb1 = (const float*)d_in[15];
    const float* fsW2 = (const float*)d_in[16];
    const float* fsb2 = (const float*)d_in[17];
    const float* foW1 = (const float*)d_in[18];
    const float* fob1 = (const float*)d_in[19];
    const float* foW2 = (const float*)d_in[20];
    const float* fob2 = (const float*)d_in[21];

    char* ws = (char*)d_ws;
    ushort* qh     = (ushort*)(ws + 0);            // 4,194,304
    ushort* kh     = (ushort*)(ws + 4194304);      // 4,194,304
    ushort* vh     = (ushort*)(ws + 8388608);      // 4,194,304
    ushort* ctxb   = (ushort*)(ws + 12582912);     // 4,194,304 (bf16)
    uint4*  bfrag1 = (uint4*)(ws + 16777216);      //     8,192
    uint4*  bfrag2 = (uint4*)(ws + 16785408);      //     4,096
    ushort* mlpb   = (ushort*)(ws + 23080960);     // 16,777,216 (permuted layout)
    ushort* qb     = (ushort*)(ws + 39858176);     // 4,194,304 (bf16 q)
    ushort* kb     = (ushort*)(ws + 44052480);     // 4,194,304
    ushort* vb     = (ushort*)(ws + 48246784);     // 4,194,304
    ushort* Wqt    = (ushort*)(ws + 52441088);     //   524,288 (bf16 W^T)
    ushort* Wkt    = (ushort*)(ws + 52965376);     //   524,288
    ushort* Wvt    = (ushort*)(ws + 53489664);     //   524,288
    ushort* Wot    = (ushort*)(ws + 54013952);     //   524,288

    cvt_prep<<<dim3(1024, 4), 256, 0, stream>>>(q, k, v, Wq, Wk, Wv, Wo,
                                                fsW1, foW1, fsW2, foW2,
                                                qb, kb, vb, Wqt, Wkt, Wvt, Wot,
                                                bfrag1, bfrag2);
    proj_kernel<<<dim3(32, 8, 3), 256, 0, stream>>>(qb, kb, vb, Wqt, Wkt, Wvt,
                                                    bq, bk, bv, qh, kh, vh);
    pair_bias_mfma<<<dim3(64, B_), 256, 0, stream>>>(sf, of, fsW1, fsb1, foW1, fob1,
                                                     fsb2, fob2, bfrag1, bfrag2, mlpb);
    attn_kernel<<<512, 256, 0, stream>>>(qh, kh, vh, tree, mlpb, ctxb);
    outproj_kernel<<<dim3(64, 8), 256, 0, stream>>>(ctxb, Wot, bo, (float*)d_out);
}